// Round 4
// baseline (558.912 us; speedup 1.0000x reference)
//
#include <hip/hip_runtime.h>
#include <stdint.h>

typedef _Float16 f16;
typedef _Float16 f16x8 __attribute__((ext_vector_type(8)));
typedef _Float16 f16x4 __attribute__((ext_vector_type(4)));
typedef float f32x4 __attribute__((ext_vector_type(4)));

constexpr int EMB = 512;
constexpr int SEQ = 1024;
constexpr int NH = 8;
constexpr int DHEAD = 64;
constexpr int NTOK = 8192;  // B*S

#define GAS __attribute__((address_space(1)))
#define LAS __attribute__((address_space(3)))

#if __has_builtin(__builtin_amdgcn_exp2f)
#define EXP2F(x) __builtin_amdgcn_exp2f(x)
#else
#define EXP2F(x) exp2f(x)
#endif

static __device__ __forceinline__ void gload_lds16(const void* g, void* l) {
  __builtin_amdgcn_global_load_lds((const GAS void*)g, (LAS void*)l, 16, 0, 0);
}

// ---------------- weight / input packing ----------------

__global__ void k_pack_w(const float* __restrict__ Wq, const float* __restrict__ Wk,
                         const float* __restrict__ Wv, const float* __restrict__ Wo,
                         f16* __restrict__ wqkv, f16* __restrict__ wo) {
  int tid = blockIdx.x * 256 + threadIdx.x;
  if (tid < 2 * 1536 * 128) {  // qkv: [L][1536][512], 4 elems/thread
    int e4 = tid & 127;
    int f = (tid >> 7) % 1536;
    int l = tid / (128 * 1536);
    int part = f >> 9, fr = f & 511;
    const float* src = (part == 0 ? Wq : part == 1 ? Wk : Wv) + (size_t)l * EMB * EMB + (size_t)fr * EMB + e4 * 4;
    float4 v = *(const float4*)src;
    f16x4 hv = {(f16)v.x, (f16)v.y, (f16)v.z, (f16)v.w};
    *(f16x4*)(wqkv + ((size_t)l * 1536 + f) * EMB + e4 * 4) = hv;
  }
  if (tid < 2 * 512 * 128) {  // wo: [L][512][512]
    int e4 = tid & 127;
    int f = (tid >> 7) % 512;
    int l = tid / (128 * 512);
    float4 v = *(const float4*)(Wo + (size_t)l * EMB * EMB + (size_t)f * EMB + e4 * 4);
    f16x4 hv = {(f16)v.x, (f16)v.y, (f16)v.z, (f16)v.w};
    *(f16x4*)(wo + ((size_t)l * 512 + f) * EMB + e4 * 4) = hv;
  }
}

__global__ void k_pack_b(const float* __restrict__ bq, const float* __restrict__ bk,
                         const float* __restrict__ bv, float* __restrict__ bqkv) {
  int tid = blockIdx.x * 256 + threadIdx.x;
  if (tid < 2 * 1536) {
    int f = tid % 1536, l = tid / 1536;
    int part = f >> 9, fr = f & 511;
    bqkv[tid] = (part == 0 ? bq : part == 1 ? bk : bv)[l * EMB + fr];
  }
}

__global__ void k_cvt(const float* __restrict__ x, f16* __restrict__ out) {
  int i = (blockIdx.x * 256 + threadIdx.x) * 8;
  float4 a = *(const float4*)(x + i);
  float4 b = *(const float4*)(x + i + 4);
  f16x8 h = {(f16)a.x, (f16)a.y, (f16)a.z, (f16)a.w, (f16)b.x, (f16)b.y, (f16)b.z, (f16)b.w};
  *(f16x8*)(out + i) = h;
}

// adj -> f16 pre-scaled by 0.125*log2(e), packed in MFMA C-fragment order:
// adjP[((qrow*16 + tile)*16 + lanelow)*4 + n] = adj[qrow][tile*64 + n*16 + lanelow] * c
__global__ void k_pack_adjP(const float* __restrict__ adj, f16* __restrict__ adjP) {
  int tid = blockIdx.x * 256 + threadIdx.x;  // 262144 total
  int lo = tid & 15, t = (tid >> 4) & 15, qrow = tid >> 8;
  const float c = 0.125f * 1.44269504088896f;
  const float* row = adj + (size_t)qrow * SEQ + t * 64 + lo;
  f16x4 v = {(f16)(row[0] * c), (f16)(row[16] * c), (f16)(row[32] * c), (f16)(row[48] * c)};
  *(f16x4*)(adjP + (size_t)tid * 4) = v;
}

// ---------------- GEMM: C[M,N] = A[M,512] * Bw[N,512]^T + bias ----------------
// 128x128 tile, BK=64, 4 waves (2x2) each 64x64 via 4x4 frags of 16x16x32.
// LDS: [128 rows][8 chunks of 16B], XOR-swizzled chunk ^= (row&7).
// MODE 0: write f32 U.  MODE 1: scatter Q,K -> [B,H,S,D], V -> Vt [B,H,D,S] (f16).

template <int MODE>
__global__ __launch_bounds__(256) void k_gemm(const f16* __restrict__ A, const f16* __restrict__ Bw,
                                              const float* __restrict__ bias, float* __restrict__ Uout,
                                              f16* __restrict__ Qo, f16* __restrict__ Ko,
                                              f16* __restrict__ Vt) {
  __shared__ f16x8 sA[1024];  // 16 KB
  __shared__ f16x8 sB[1024];
  const int tid = threadIdx.x;
  const int lane = tid & 63;
  const int lanelow = lane & 15, lanehi = lane >> 4;
  const int wave = tid >> 6;
  const int wm = wave >> 1, wn = wave & 1;
  const int m0 = blockIdx.y * 128, n0 = blockIdx.x * 128;

  f32x4 acc[4][4] = {};

  const f16* aB = A + (size_t)m0 * EMB;
  const f16* bB = Bw + (size_t)n0 * EMB;

  int srow[4], scl[4];
#pragma unroll
  for (int p = 0; p < 4; ++p) {
    int i = p * 256 + tid;
    srow[p] = i >> 3;
    scl[p] = (i & 7) ^ (srow[p] & 7);  // pre-swizzled global chunk for linear LDS dest
  }

  for (int kt = 0; kt < EMB; kt += 64) {
#pragma unroll
    for (int p = 0; p < 4; ++p) {
      int i = p * 256 + tid;
      gload_lds16(aB + (size_t)srow[p] * EMB + kt + scl[p] * 8, (char*)sA + i * 16);
      gload_lds16(bB + (size_t)srow[p] * EMB + kt + scl[p] * 8, (char*)sB + i * 16);
    }
    __syncthreads();
#pragma unroll
    for (int ks = 0; ks < 2; ++ks) {
      f16x8 af[4], bf[4];
#pragma unroll
      for (int m = 0; m < 4; ++m) {
        int r = wm * 64 + m * 16 + lanelow;
        af[m] = sA[r * 8 + ((ks * 4 + lanehi) ^ (r & 7))];
      }
#pragma unroll
      for (int n = 0; n < 4; ++n) {
        int r = wn * 64 + n * 16 + lanelow;
        bf[n] = sB[r * 8 + ((ks * 4 + lanehi) ^ (r & 7))];
      }
#pragma unroll
      for (int m = 0; m < 4; ++m)
#pragma unroll
        for (int n = 0; n < 4; ++n)
          acc[m][n] = __builtin_amdgcn_mfma_f32_16x16x32_f16(af[m], bf[n], acc[m][n], 0, 0, 0);
    }
    __syncthreads();
  }

  // epilogue: C/D layout col = lane&15, row = (lane>>4)*4 + j
#pragma unroll
  for (int n = 0; n < 4; ++n) {
    int col = n0 + wn * 64 + n * 16 + lanelow;
    float bv = bias[col];
#pragma unroll
    for (int m = 0; m < 4; ++m) {
      int rbase = m0 + wm * 64 + m * 16 + lanehi * 4;
#pragma unroll
      for (int j = 0; j < 4; ++j) {
        float v = acc[m][n][j] + bv;
        int row = rbase + j;
        if (MODE == 0) {
          Uout[(size_t)row * EMB + col] = v;
        } else {
          int part = col >> 9, fr = col & 511;
          int hh = fr >> 6, d = fr & 63;
          int b = row >> 10, s = row & 1023;
          int bh = b * NH + hh;
          if (part == 0)
            Qo[((size_t)bh * SEQ + s) * DHEAD + d] = (f16)v;
          else if (part == 1)
            Ko[((size_t)bh * SEQ + s) * DHEAD + d] = (f16)v;
          else
            Vt[((size_t)bh * DHEAD + d) * SEQ + s] = (f16)v;
        }
      }
    }
  }
}

// ---------------- flash attention: R0 structure + register software-pipeline ------------
// R3: back to the 77us R0 base (4 waves x 32 q-rows, 512 blocks x 256 thr, no
// launch_bounds cap -> no spills). Full unroll of 16 K-tiles; per tile issue
// V(t) at top, reload K(t+1) right after QK consumes K(t), reload adj(t+1)
// after the exp phase. Every global load gets >=350cyc of compute cover;
// occupancy stays grid-limited at 2 waves/SIMD so the extra VGPRs are free.

__global__ __launch_bounds__(256) void k_attn(const f16* __restrict__ Q, const f16* __restrict__ K,
                                              const f16* __restrict__ Vt, const f16* __restrict__ adjP,
                                              f16* __restrict__ Ob) {
  __shared__ __align__(16) f16 Pl[4 * 2048];  // per-wave [32][64] f16, XOR-swizzled chunks
  const int tid = threadIdx.x;
  const int lane = tid & 63;
  const int lanelow = lane & 15, lanehi = lane >> 4;
  const int wave = tid >> 6;
  f16* Plw = Pl + wave * 2048;

  const int bh = blockIdx.x >> 3;
  const int qblk = blockIdx.x & 7;
  const int b = bh >> 3, hh = bh & 7;
  const int q0 = qblk * 128 + wave * 32;

  // hoist Q fragments
  f16x8 qf[2][2];
#pragma unroll
  for (int m = 0; m < 2; ++m)
#pragma unroll
    for (int ks = 0; ks < 2; ++ks)
      qf[m][ks] = *(const f16x8*)(Q + ((size_t)bh * SEQ + q0 + m * 16 + lanelow) * DHEAD + ks * 32 + lanehi * 8);

  // per-lane base pointers
  const f16* Kb = K + (size_t)bh * SEQ * DHEAD + (size_t)lanelow * DHEAD + lanehi * 8;
  const f16* Vb = Vt + (size_t)bh * DHEAD * SEQ + (size_t)lanelow * SEQ + lanehi * 8;
  const f16* Ab = adjP + ((size_t)(q0 + lanehi * 4) * 256 + lanelow) * 4;

  f32x4 oacc[2][4] = {};
  float lpart[2][4] = {};

  f16x8 kb[2][4];  // K(t) fragments [ks][n]
  f16x4 ab[2][4];  // adj(t) C-frag packed [m][j]

#define LOAD_K(ktv)                                                                   \
  {                                                                                   \
    _Pragma("unroll") for (int ks = 0; ks < 2; ++ks)                                  \
        _Pragma("unroll") for (int n = 0; n < 4; ++n)                                 \
            kb[ks][n] = *(const f16x8*)(Kb + ((size_t)(ktv) + n * 16) * DHEAD + ks * 32); \
  }
#define LOAD_A(tv)                                                                    \
  {                                                                                   \
    _Pragma("unroll") for (int m = 0; m < 2; ++m)                                     \
        _Pragma("unroll") for (int j = 0; j < 4; ++j)                                 \
            ab[m][j] = *(const f16x4*)(Ab + ((size_t)(m * 16 + j) * 256 + (tv)*16) * 4); \
  }

  LOAD_K(0);
  LOAD_A(0);

#pragma unroll
  for (int t = 0; t < 16; ++t) {
    const int kt = t * 64;
    // V(t): issued first, consumed at PV (cover = QK + exp)
    f16x8 vb[2][4];
#pragma unroll
    for (int ks = 0; ks < 2; ++ks)
#pragma unroll
      for (int n = 0; n < 4; ++n)
        vb[ks][n] = *(const f16x8*)(Vb + (size_t)(n * 16) * SEQ + kt + ks * 32);

    // QK^T with K(t) (prefetched last tile)
    f32x4 sacc[2][4] = {};
#pragma unroll
    for (int ks = 0; ks < 2; ++ks)
#pragma unroll
      for (int m = 0; m < 2; ++m)
#pragma unroll
        for (int n = 0; n < 4; ++n)
          sacc[m][n] = __builtin_amdgcn_mfma_f32_16x16x32_f16(qf[m][ks], kb[ks][n], sacc[m][n], 0, 0, 0);

    // snapshot adj(t), then prefetch K(t+1) (cover = exp + PV)
    f16x4 acur[2][4];
#pragma unroll
    for (int m = 0; m < 2; ++m)
#pragma unroll
      for (int j = 0; j < 4; ++j) acur[m][j] = ab[m][j];
    if (t < 15) LOAD_K(kt + 64);

    // p = exp2(s * a2); lane-local row sums; stage P in per-wave LDS
#pragma unroll
    for (int m = 0; m < 2; ++m)
#pragma unroll
      for (int j = 0; j < 4; ++j) {
        const int prow = m * 16 + lanehi * 4 + j;
        const f16x4 a4 = acur[m][j];
#pragma unroll
        for (int n = 0; n < 4; ++n) {
          float p = EXP2F(sacc[m][n][j] * (float)a4[n]);
          lpart[m][j] += p;
          Plw[prow * 64 + (((n * 2 + (lanelow >> 3)) ^ (prow & 7)) * 8) + (lanelow & 7)] = (f16)p;
        }
      }

    // prefetch adj(t+1) (cover = PV + next QK)
    if (t < 15) LOAD_A(t + 1);

    // O += P V
#pragma unroll
    for (int ks = 0; ks < 2; ++ks) {
      f16x8 pa[2];
#pragma unroll
      for (int m = 0; m < 2; ++m)
        pa[m] = *(const f16x8*)(Plw + (m * 16 + lanelow) * 64 + (((ks * 4 + lanehi) ^ (lanelow & 7)) * 8));
#pragma unroll
      for (int m = 0; m < 2; ++m)
#pragma unroll
        for (int n = 0; n < 4; ++n)
          oacc[m][n] = __builtin_amdgcn_mfma_f32_16x16x32_f16(pa[m], vb[ks][n], oacc[m][n], 0, 0, 0);
    }
  }
#undef LOAD_K
#undef LOAD_A

  // final: one cross-lane reduce of row sums, normalize, write O to [B,S,E] f16
  float linv[2][4];
#pragma unroll
  for (int m = 0; m < 2; ++m)
#pragma unroll
    for (int j = 0; j < 4; ++j) {
      float l = lpart[m][j];
#pragma unroll
      for (int off = 1; off < 16; off <<= 1) l += __shfl_xor(l, off, 16);
      linv[m][j] = 1.0f / l;
    }
#pragma unroll
  for (int m = 0; m < 2; ++m)
#pragma unroll
    for (int n = 0; n < 4; ++n)
#pragma unroll
      for (int j = 0; j < 4; ++j) {
        int qrow = q0 + m * 16 + lanehi * 4 + j;
        float v = oacc[m][n][j] * linv[m][j];
        Ob[((size_t)b * SEQ + qrow) * EMB + hh * DHEAD + n * 16 + lanelow] = (f16)v;
      }
}

// ---------------- residual + layernorm (wave per row) ----------------

__global__ __launch_bounds__(256) void k_ln(const float* __restrict__ xin, const float* __restrict__ Uin,
                                            const float* __restrict__ gamma, const float* __restrict__ beta,
                                            float* __restrict__ xout, f16* __restrict__ xh_out) {
  const int row = blockIdx.x * 4 + (threadIdx.x >> 6);
  const int lane = threadIdx.x & 63;
  const size_t base = (size_t)row * EMB + lane * 8;
  float u[8];
  {
    float4 a0 = *(const float4*)(xin + base);
    float4 a1 = *(const float4*)(xin + base + 4);
    float4 c0 = *(const float4*)(Uin + base);
    float4 c1 = *(const float4*)(Uin + base + 4);
    u[0] = a0.x + c0.x; u[1] = a0.y + c0.y; u[2] = a0.z + c0.z; u[3] = a0.w + c0.w;
    u[4] = a1.x + c1.x; u[5] = a1.y + c1.y; u[6] = a1.z + c1.z; u[7] = a1.w + c1.w;
  }
  float s = 0.f;
#pragma unroll
  for (int i = 0; i < 8; ++i) s += u[i];
#pragma unroll
  for (int off = 1; off < 64; off <<= 1) s += __shfl_xor(s, off, 64);
  const float mu = s * (1.0f / EMB);
  float v = 0.f;
#pragma unroll
  for (int i = 0; i < 8; ++i) { float d = u[i] - mu; v += d * d; }
#pragma unroll
  for (int off = 1; off < 64; off <<= 1) v += __shfl_xor(v, off, 64);
  const float rs = rsqrtf(v * (1.0f / EMB) + 1e-5f);
  const int ci = lane * 8;
  float4 g0 = *(const float4*)(gamma + ci);
  float4 g1 = *(const float4*)(gamma + ci + 4);
  float4 b0 = *(const float4*)(beta + ci);
  float4 b1 = *(const float4*)(beta + ci + 4);
  float g[8] = {g0.x, g0.y, g0.z, g0.w, g1.x, g1.y, g1.z, g1.w};
  float be[8] = {b0.x, b0.y, b0.z, b0.w, b1.x, b1.y, b1.z, b1.w};
  float o[8];
#pragma unroll
  for (int i = 0; i < 8; ++i) o[i] = (u[i] - mu) * rs * g[i] + be[i];
  float4 o0 = {o[0], o[1], o[2], o[3]}, o1 = {o[4], o[5], o[6], o[7]};
  *(float4*)(xout + base) = o0;
  *(float4*)(xout + base + 4) = o1;
  if (xh_out) {
    f16x8 hv = {(f16)o[0], (f16)o[1], (f16)o[2], (f16)o[3], (f16)o[4], (f16)o[5], (f16)o[6], (f16)o[7]};
    *(f16x8*)(xh_out + base) = hv;
  }
}

// ---------------- launch ----------------

extern "C" void kernel_launch(void* const* d_in, const int* in_sizes, int n_in,
                              void* d_out, int out_size, void* d_ws, size_t ws_size,
                              hipStream_t stream) {
  (void)in_sizes; (void)n_in; (void)out_size; (void)ws_size;
  const float* x = (const float*)d_in[0];
  const float* adj = (const float*)d_in[1];
  const float* Wq = (const float*)d_in[2];
  const float* bq = (const float*)d_in[3];
  const float* Wk = (const float*)d_in[4];
  const float* bk = (const float*)d_in[5];
  const float* Wv = (const float*)d_in[6];
  const float* bv = (const float*)d_in[7];
  const float* Wo = (const float*)d_in[8];
  const float* bo = (const float*)d_in[9];
  const float* gamma = (const float*)d_in[10];
  const float* beta = (const float*)d_in[11];

  char* ws = (char*)d_ws;
  size_t off = 0;
  auto alloc = [&](size_t bytes) {
    char* p = ws + off;
    off += (bytes + 255) & ~(size_t)255;
    return p;
  };
  f16* wqkv = (f16*)alloc((size_t)2 * 1536 * 512 * sizeof(f16));
  f16* wo = (f16*)alloc((size_t)2 * 512 * 512 * sizeof(f16));
  float* bqkv = (float*)alloc((size_t)2 * 1536 * sizeof(float));
  f16* adjP = (f16*)alloc((size_t)SEQ * SEQ * sizeof(f16));
  f16* xh = (f16*)alloc((size_t)NTOK * EMB * sizeof(f16));
  f16* Qb = (f16*)alloc((size_t)NTOK * EMB * sizeof(f16));
  f16* Kb = (f16*)alloc((size_t)NTOK * EMB * sizeof(f16));
  f16* Vtb = (f16*)alloc((size_t)NTOK * EMB * sizeof(f16));
  f16* Ob = (f16*)alloc((size_t)NTOK * EMB * sizeof(f16));
  float* U = (float*)alloc((size_t)NTOK * EMB * sizeof(float));
  float* x1 = (float*)alloc((size_t)NTOK * EMB * sizeof(float));

  k_pack_w<<<1536, 256, 0, stream>>>(Wq, Wk, Wv, Wo, wqkv, wo);
  k_pack_b<<<12, 256, 0, stream>>>(bq, bk, bv, bqkv);
  k_pack_adjP<<<1024, 256, 0, stream>>>(adj, adjP);
  k_cvt<<<2048, 256, 0, stream>>>(x, xh);

  const float* xcur = x;
  for (int l = 0; l < 2; ++l) {
    k_gemm<1><<<dim3(12, 64), 256, 0, stream>>>(xh, wqkv + (size_t)l * 1536 * 512, bqkv + l * 1536,
                                                nullptr, Qb, Kb, Vtb);
    k_attn<<<512, 256, 0, stream>>>(Qb, Kb, Vtb, adjP, Ob);
    k_gemm<0><<<dim3(4, 64), 256, 0, stream>>>(Ob, wo + (size_t)l * 512 * 512, bo + l * 512,
                                               U, nullptr, nullptr, nullptr);
    float* xnext = (l == 0) ? x1 : (float*)d_out;
    k_ln<<<2048, 256, 0, stream>>>(xcur, U, gamma + l * 512, beta + l * 512, xnext,
                                   (l == 0) ? xh : nullptr);
    xcur = xnext;
  }
}

// Round 5
// 227.520 us; speedup vs baseline: 2.4565x; 2.4565x over previous
//
#include <hip/hip_runtime.h>
#include <stdint.h>

typedef _Float16 f16;
typedef _Float16 f16x8 __attribute__((ext_vector_type(8)));
typedef _Float16 f16x4 __attribute__((ext_vector_type(4)));
typedef float f32x4 __attribute__((ext_vector_type(4)));

constexpr int EMB = 512;
constexpr int SEQ = 1024;
constexpr int NH = 8;
constexpr int DHEAD = 64;
constexpr int NTOK = 8192;  // B*S

#define GAS __attribute__((address_space(1)))
#define LAS __attribute__((address_space(3)))

#if __has_builtin(__builtin_amdgcn_exp2f)
#define EXP2F(x) __builtin_amdgcn_exp2f(x)
#else
#define EXP2F(x) exp2f(x)
#endif

static __device__ __forceinline__ void gload_lds16(const void* g, void* l) {
  __builtin_amdgcn_global_load_lds((const GAS void*)g, (LAS void*)l, 16, 0, 0);
}

// ---------------- weight / input packing ----------------

__global__ void k_pack_w(const float* __restrict__ Wq, const float* __restrict__ Wk,
                         const float* __restrict__ Wv, const float* __restrict__ Wo,
                         f16* __restrict__ wqkv, f16* __restrict__ wo) {
  int tid = blockIdx.x * 256 + threadIdx.x;
  if (tid < 2 * 1536 * 128) {  // qkv: [L][1536][512], 4 elems/thread
    int e4 = tid & 127;
    int f = (tid >> 7) % 1536;
    int l = tid / (128 * 1536);
    int part = f >> 9, fr = f & 511;
    const float* src = (part == 0 ? Wq : part == 1 ? Wk : Wv) + (size_t)l * EMB * EMB + (size_t)fr * EMB + e4 * 4;
    float4 v = *(const float4*)src;
    f16x4 hv = {(f16)v.x, (f16)v.y, (f16)v.z, (f16)v.w};
    *(f16x4*)(wqkv + ((size_t)l * 1536 + f) * EMB + e4 * 4) = hv;
  }
  if (tid < 2 * 512 * 128) {  // wo: [L][512][512]
    int e4 = tid & 127;
    int f = (tid >> 7) % 512;
    int l = tid / (128 * 512);
    float4 v = *(const float4*)(Wo + (size_t)l * EMB * EMB + (size_t)f * EMB + e4 * 4);
    f16x4 hv = {(f16)v.x, (f16)v.y, (f16)v.z, (f16)v.w};
    *(f16x4*)(wo + ((size_t)l * 512 + f) * EMB + e4 * 4) = hv;
  }
}

__global__ void k_pack_b(const float* __restrict__ bq, const float* __restrict__ bk,
                         const float* __restrict__ bv, float* __restrict__ bqkv) {
  int tid = blockIdx.x * 256 + threadIdx.x;
  if (tid < 2 * 1536) {
    int f = tid % 1536, l = tid / 1536;
    int part = f >> 9, fr = f & 511;
    bqkv[tid] = (part == 0 ? bq : part == 1 ? bk : bv)[l * EMB + fr];
  }
}

__global__ void k_cvt(const float* __restrict__ x, f16* __restrict__ out) {
  int i = (blockIdx.x * 256 + threadIdx.x) * 8;
  float4 a = *(const float4*)(x + i);
  float4 b = *(const float4*)(x + i + 4);
  f16x8 h = {(f16)a.x, (f16)a.y, (f16)a.z, (f16)a.w, (f16)b.x, (f16)b.y, (f16)b.z, (f16)b.w};
  *(f16x8*)(out + i) = h;
}

// adj -> f16 pre-scaled by 0.125*log2(e), packed in MFMA C-fragment order:
// adjP[((qrow*16 + tile)*16 + lanelow)*4 + n] = adj[qrow][tile*64 + n*16 + lanelow] * c
__global__ void k_pack_adjP(const float* __restrict__ adj, f16* __restrict__ adjP) {
  int tid = blockIdx.x * 256 + threadIdx.x;  // 262144 total
  int lo = tid & 15, t = (tid >> 4) & 15, qrow = tid >> 8;
  const float c = 0.125f * 1.44269504088896f;
  const float* row = adj + (size_t)qrow * SEQ + t * 64 + lo;
  f16x4 v = {(f16)(row[0] * c), (f16)(row[16] * c), (f16)(row[32] * c), (f16)(row[48] * c)};
  *(f16x4*)(adjP + (size_t)tid * 4) = v;
}

// ---------------- GEMM: C[M,N] = A[M,512] * Bw[N,512]^T + bias ----------------
// 128x128 tile, BK=64, 4 waves (2x2) each 64x64 via 4x4 frags of 16x16x32.
// LDS: [128 rows][8 chunks of 16B], XOR-swizzled chunk ^= (row&7).
// MODE 0: write f32 U.  MODE 1: scatter Q,K -> [B,H,S,D], V -> Vt [B,H,D,S] (f16).

template <int MODE>
__global__ __launch_bounds__(256) void k_gemm(const f16* __restrict__ A, const f16* __restrict__ Bw,
                                              const float* __restrict__ bias, float* __restrict__ Uout,
                                              f16* __restrict__ Qo, f16* __restrict__ Ko,
                                              f16* __restrict__ Vt) {
  __shared__ f16x8 sA[1024];  // 16 KB
  __shared__ f16x8 sB[1024];
  const int tid = threadIdx.x;
  const int lane = tid & 63;
  const int lanelow = lane & 15, lanehi = lane >> 4;
  const int wave = tid >> 6;
  const int wm = wave >> 1, wn = wave & 1;
  const int m0 = blockIdx.y * 128, n0 = blockIdx.x * 128;

  f32x4 acc[4][4] = {};

  const f16* aB = A + (size_t)m0 * EMB;
  const f16* bB = Bw + (size_t)n0 * EMB;

  int srow[4], scl[4];
#pragma unroll
  for (int p = 0; p < 4; ++p) {
    int i = p * 256 + tid;
    srow[p] = i >> 3;
    scl[p] = (i & 7) ^ (srow[p] & 7);  // pre-swizzled global chunk for linear LDS dest
  }

  for (int kt = 0; kt < EMB; kt += 64) {
#pragma unroll
    for (int p = 0; p < 4; ++p) {
      int i = p * 256 + tid;
      gload_lds16(aB + (size_t)srow[p] * EMB + kt + scl[p] * 8, (char*)sA + i * 16);
      gload_lds16(bB + (size_t)srow[p] * EMB + kt + scl[p] * 8, (char*)sB + i * 16);
    }
    __syncthreads();
#pragma unroll
    for (int ks = 0; ks < 2; ++ks) {
      f16x8 af[4], bf[4];
#pragma unroll
      for (int m = 0; m < 4; ++m) {
        int r = wm * 64 + m * 16 + lanelow;
        af[m] = sA[r * 8 + ((ks * 4 + lanehi) ^ (r & 7))];
      }
#pragma unroll
      for (int n = 0; n < 4; ++n) {
        int r = wn * 64 + n * 16 + lanelow;
        bf[n] = sB[r * 8 + ((ks * 4 + lanehi) ^ (r & 7))];
      }
#pragma unroll
      for (int m = 0; m < 4; ++m)
#pragma unroll
        for (int n = 0; n < 4; ++n)
          acc[m][n] = __builtin_amdgcn_mfma_f32_16x16x32_f16(af[m], bf[n], acc[m][n], 0, 0, 0);
    }
    __syncthreads();
  }

  // epilogue: C/D layout col = lane&15, row = (lane>>4)*4 + j
#pragma unroll
  for (int n = 0; n < 4; ++n) {
    int col = n0 + wn * 64 + n * 16 + lanelow;
    float bv = bias[col];
#pragma unroll
    for (int m = 0; m < 4; ++m) {
      int rbase = m0 + wm * 64 + m * 16 + lanehi * 4;
#pragma unroll
      for (int j = 0; j < 4; ++j) {
        float v = acc[m][n][j] + bv;
        int row = rbase + j;
        if (MODE == 0) {
          Uout[(size_t)row * EMB + col] = v;
        } else {
          int part = col >> 9, fr = col & 511;
          int hh = fr >> 6, d = fr & 63;
          int b = row >> 10, s = row & 1023;
          int bh = b * NH + hh;
          if (part == 0)
            Qo[((size_t)bh * SEQ + s) * DHEAD + d] = (f16)v;
          else if (part == 1)
            Ko[((size_t)bh * SEQ + s) * DHEAD + d] = (f16)v;
          else
            Vt[((size_t)bh * DHEAD + d) * SEQ + s] = (f16)v;
        }
      }
    }
  }
}

// ---------------- flash attention: LDS-shared K/V tiles, double-buffered ------------
// R4 theory: R0 was bound by redundant K/V request traffic (each of 4 waves
// independently re-read K,V: ~770 MB/layer streaming from L3). Fix: stage the
// 64x64 K-tile and V-tile in LDS ONCE per block via global_load_lds (zero VGPR
// cost -- the R2/R3 spill lesson), double-buffered 2-phase schedule: issue
// STAGE(t+1) into buf^1 at top, compute tile t from buf, one __syncthreads()
// (implicit vmcnt0 after ~1000cy cover) per tile. 4x less K/V traffic.
// adj stays per-wave in registers (f16 C-frag packed, next-tile snapshot
// prefetch = only 16 VGPRs persistent).

__global__ __launch_bounds__(256) void k_attn(const f16* __restrict__ Q, const f16* __restrict__ K,
                                              const f16* __restrict__ Vt, const f16* __restrict__ adjP,
                                              f16* __restrict__ Ob) {
  __shared__ __align__(16) f16 sK[2][4096];   // [buf][64 rows x 8 chunks], swizzled
  __shared__ __align__(16) f16 sV[2][4096];
  __shared__ __align__(16) f16 Pl[4 * 2048];  // per-wave [32][64] P, swizzled
  const int tid = threadIdx.x;
  const int lane = tid & 63;
  const int lanelow = lane & 15, lanehi = lane >> 4;
  const int wave = tid >> 6;
  f16* Plw = Pl + wave * 2048;

  const int bh = blockIdx.x >> 3;
  const int qblk = blockIdx.x & 7;
  const int b = bh >> 3, hh = bh & 7;
  const int q0 = qblk * 128 + wave * 32;

  const f16* Kbase = K + (size_t)bh * SEQ * DHEAD;
  const f16* Vbase = Vt + (size_t)bh * DHEAD * SEQ;

  // staging chunk map: thread handles chunks tid and tid+256 of each tile
  // (512 chunks x 16B = 8KB). Linear LDS dest, inverse-swizzled global source.
  const int c0 = tid, c1 = tid + 256;
  const int r0 = c0 >> 3, ch0 = (c0 & 7) ^ (r0 & 7);
  const int r1 = c1 >> 3, ch1 = (c1 & 7) ^ (r1 & 7);

#define STAGE(tv, bufv)                                                                  \
  {                                                                                      \
    const int kts = (tv)*64;                                                             \
    gload_lds16(Kbase + (size_t)(kts + r0) * DHEAD + ch0 * 8, (char*)sK[bufv] + c0 * 16); \
    gload_lds16(Kbase + (size_t)(kts + r1) * DHEAD + ch1 * 8, (char*)sK[bufv] + c1 * 16); \
    gload_lds16(Vbase + (size_t)r0 * SEQ + kts + ch0 * 8, (char*)sV[bufv] + c0 * 16);     \
    gload_lds16(Vbase + (size_t)r1 * SEQ + kts + ch1 * 8, (char*)sV[bufv] + c1 * 16);     \
  }

  // hoist Q fragments
  f16x8 qf[2][2];
#pragma unroll
  for (int m = 0; m < 2; ++m)
#pragma unroll
    for (int ks = 0; ks < 2; ++ks)
      qf[m][ks] = *(const f16x8*)(Q + ((size_t)bh * SEQ + q0 + m * 16 + lanelow) * DHEAD + ks * 32 + lanehi * 8);

  // adj register prefetch (f16 C-frag packed): 8 x f16x4 = 8 VGPRs
  const f16* Ab = adjP + ((size_t)(q0 + lanehi * 4) * 256 + lanelow) * 4;
  f16x4 ab[2][4];
#define LOAD_A(tv)                                                                    \
  {                                                                                   \
    _Pragma("unroll") for (int m = 0; m < 2; ++m)                                     \
        _Pragma("unroll") for (int j = 0; j < 4; ++j)                                 \
            ab[m][j] = *(const f16x4*)(Ab + ((size_t)(m * 16 + j) * 256 + (tv)*16) * 4); \
  }

  f32x4 oacc[2][4] = {};
  float lpart[2][4] = {};

  STAGE(0, 0);
  LOAD_A(0);
  __syncthreads();

  int cur = 0;
  for (int t = 0; t < 16; ++t) {
    // issue next tile's staging into the other buffer (cover = whole compute phase)
    if (t < 15) STAGE(t + 1, cur ^ 1);

    const f16* sKc = sK[cur];
    const f16* sVc = sV[cur];

    // --- QK^T from LDS K
    f32x4 sacc[2][4] = {};
#pragma unroll
    for (int ks = 0; ks < 2; ++ks) {
      f16x8 kf[4];
#pragma unroll
      for (int n = 0; n < 4; ++n) {
        int r = n * 16 + lanelow;
        kf[n] = *(const f16x8*)(sKc + (r * 8 + ((ks * 4 + lanehi) ^ (r & 7))) * 8);
      }
#pragma unroll
      for (int m = 0; m < 2; ++m)
#pragma unroll
        for (int n = 0; n < 4; ++n)
          sacc[m][n] = __builtin_amdgcn_mfma_f32_16x16x32_f16(qf[m][ks], kf[n], sacc[m][n], 0, 0, 0);
    }

    // snapshot adj(t), prefetch adj(t+1) (cover = exp + PV + next QK)
    f16x4 acur[2][4];
#pragma unroll
    for (int m = 0; m < 2; ++m)
#pragma unroll
      for (int j = 0; j < 4; ++j) acur[m][j] = ab[m][j];
    if (t < 15) LOAD_A(t + 1);

    // --- p = exp2(s * a2); lane-local row sums; stage P in per-wave LDS
#pragma unroll
    for (int m = 0; m < 2; ++m)
#pragma unroll
      for (int j = 0; j < 4; ++j) {
        const int prow = m * 16 + lanehi * 4 + j;
        const f16x4 a4 = acur[m][j];
#pragma unroll
        for (int n = 0; n < 4; ++n) {
          float p = EXP2F(sacc[m][n][j] * (float)a4[n]);
          lpart[m][j] += p;
          Plw[prow * 64 + (((n * 2 + (lanelow >> 3)) ^ (prow & 7)) * 8) + (lanelow & 7)] = (f16)p;
        }
      }

    // --- O += P V from LDS V
#pragma unroll
    for (int ks = 0; ks < 2; ++ks) {
      f16x8 pa[2], vf[4];
#pragma unroll
      for (int m = 0; m < 2; ++m)
        pa[m] = *(const f16x8*)(Plw + (m * 16 + lanelow) * 64 + (((ks * 4 + lanehi) ^ (lanelow & 7)) * 8));
#pragma unroll
      for (int n = 0; n < 4; ++n) {
        int r = n * 16 + lanelow;
        vf[n] = *(const f16x8*)(sVc + (r * 8 + ((ks * 4 + lanehi) ^ (r & 7))) * 8);
      }
#pragma unroll
      for (int m = 0; m < 2; ++m)
#pragma unroll
        for (int n = 0; n < 4; ++n)
          oacc[m][n] = __builtin_amdgcn_mfma_f32_16x16x32_f16(pa[m], vf[n], oacc[m][n], 0, 0, 0);
    }

    __syncthreads();  // implicit vmcnt(0)+lgkmcnt(0): next buffer staged, all waves done with cur
    cur ^= 1;
  }
#undef STAGE
#undef LOAD_A

  // final: one cross-lane reduce of row sums, normalize, write O to [B,S,E] f16
  float linv[2][4];
#pragma unroll
  for (int m = 0; m < 2; ++m)
#pragma unroll
    for (int j = 0; j < 4; ++j) {
      float l = lpart[m][j];
#pragma unroll
      for (int off = 1; off < 16; off <<= 1) l += __shfl_xor(l, off, 16);
      linv[m][j] = 1.0f / l;
    }
#pragma unroll
  for (int m = 0; m < 2; ++m)
#pragma unroll
    for (int n = 0; n < 4; ++n)
#pragma unroll
      for (int j = 0; j < 4; ++j) {
        int qrow = q0 + m * 16 + lanehi * 4 + j;
        float v = oacc[m][n][j] * linv[m][j];
        Ob[((size_t)b * SEQ + qrow) * EMB + hh * DHEAD + n * 16 + lanelow] = (f16)v;
      }
}

// ---------------- residual + layernorm (wave per row) ----------------

__global__ __launch_bounds__(256) void k_ln(const float* __restrict__ xin, const float* __restrict__ Uin,
                                            const float* __restrict__ gamma, const float* __restrict__ beta,
                                            float* __restrict__ xout, f16* __restrict__ xh_out) {
  const int row = blockIdx.x * 4 + (threadIdx.x >> 6);
  const int lane = threadIdx.x & 63;
  const size_t base = (size_t)row * EMB + lane * 8;
  float u[8];
  {
    float4 a0 = *(const float4*)(xin + base);
    float4 a1 = *(const float4*)(xin + base + 4);
    float4 c0 = *(const float4*)(Uin + base);
    float4 c1 = *(const float4*)(Uin + base + 4);
    u[0] = a0.x + c0.x; u[1] = a0.y + c0.y; u[2] = a0.z + c0.z; u[3] = a0.w + c0.w;
    u[4] = a1.x + c1.x; u[5] = a1.y + c1.y; u[6] = a1.z + c1.z; u[7] = a1.w + c1.w;
  }
  float s = 0.f;
#pragma unroll
  for (int i = 0; i < 8; ++i) s += u[i];
#pragma unroll
  for (int off = 1; off < 64; off <<= 1) s += __shfl_xor(s, off, 64);
  const float mu = s * (1.0f / EMB);
  float v = 0.f;
#pragma unroll
  for (int i = 0; i < 8; ++i) { float d = u[i] - mu; v += d * d; }
#pragma unroll
  for (int off = 1; off < 64; off <<= 1) v += __shfl_xor(v, off, 64);
  const float rs = rsqrtf(v * (1.0f / EMB) + 1e-5f);
  const int ci = lane * 8;
  float4 g0 = *(const float4*)(gamma + ci);
  float4 g1 = *(const float4*)(gamma + ci + 4);
  float4 b0 = *(const float4*)(beta + ci);
  float4 b1 = *(const float4*)(beta + ci + 4);
  float g[8] = {g0.x, g0.y, g0.z, g0.w, g1.x, g1.y, g1.z, g1.w};
  float be[8] = {b0.x, b0.y, b0.z, b0.w, b1.x, b1.y, b1.z, b1.w};
  float o[8];
#pragma unroll
  for (int i = 0; i < 8; ++i) o[i] = (u[i] - mu) * rs * g[i] + be[i];
  float4 o0 = {o[0], o[1], o[2], o[3]}, o1 = {o[4], o[5], o[6], o[7]};
  *(float4*)(xout + base) = o0;
  *(float4*)(xout + base + 4) = o1;
  if (xh_out) {
    f16x8 hv = {(f16)o[0], (f16)o[1], (f16)o[2], (f16)o[3], (f16)o[4], (f16)o[5], (f16)o[6], (f16)o[7]};
    *(f16x8*)(xh_out + base) = hv;
  }
}

// ---------------- launch ----------------

extern "C" void kernel_launch(void* const* d_in, const int* in_sizes, int n_in,
                              void* d_out, int out_size, void* d_ws, size_t ws_size,
                              hipStream_t stream) {
  (void)in_sizes; (void)n_in; (void)out_size; (void)ws_size;
  const float* x = (const float*)d_in[0];
  const float* adj = (const float*)d_in[1];
  const float* Wq = (const float*)d_in[2];
  const float* bq = (const float*)d_in[3];
  const float* Wk = (const float*)d_in[4];
  const float* bk = (const float*)d_in[5];
  const float* Wv = (const float*)d_in[6];
  const float* bv = (const float*)d_in[7];
  const float* Wo = (const float*)d_in[8];
  const float* bo = (const float*)d_in[9];
  const float* gamma = (const float*)d_in[10];
  const float* beta = (const float*)d_in[11];

  char* ws = (char*)d_ws;
  size_t off = 0;
  auto alloc = [&](size_t bytes) {
    char* p = ws + off;
    off += (bytes + 255) & ~(size_t)255;
    return p;
  };
  f16* wqkv = (f16*)alloc((size_t)2 * 1536 * 512 * sizeof(f16));
  f16* wo = (f16*)alloc((size_t)2 * 512 * 512 * sizeof(f16));
  float* bqkv = (float*)alloc((size_t)2 * 1536 * sizeof(float));
  f16* adjP = (f16*)alloc((size_t)SEQ * SEQ * sizeof(f16));
  f16* xh = (f16*)alloc((size_t)NTOK * EMB * sizeof(f16));
  f16* Qb = (f16*)alloc((size_t)NTOK * EMB * sizeof(f16));
  f16* Kb = (f16*)alloc((size_t)NTOK * EMB * sizeof(f16));
  f16* Vtb = (f16*)alloc((size_t)NTOK * EMB * sizeof(f16));
  f16* Ob = (f16*)alloc((size_t)NTOK * EMB * sizeof(f16));
  float* U = (float*)alloc((size_t)NTOK * EMB * sizeof(float));
  float* x1 = (float*)alloc((size_t)NTOK * EMB * sizeof(float));

  k_pack_w<<<1536, 256, 0, stream>>>(Wq, Wk, Wv, Wo, wqkv, wo);
  k_pack_b<<<12, 256, 0, stream>>>(bq, bk, bv, bqkv);
  k_pack_adjP<<<1024, 256, 0, stream>>>(adj, adjP);
  k_cvt<<<2048, 256, 0, stream>>>(x, xh);

  const float* xcur = x;
  for (int l = 0; l < 2; ++l) {
    k_gemm<1><<<dim3(12, 64), 256, 0, stream>>>(xh, wqkv + (size_t)l * 1536 * 512, bqkv + l * 1536,
                                                nullptr, Qb, Kb, Vtb);
    k_attn<<<512, 256, 0, stream>>>(Qb, Kb, Vtb, adjP, Ob);
    k_gemm<0><<<dim3(4, 64), 256, 0, stream>>>(Ob, wo + (size_t)l * 512 * 512, bo + l * 512,
                                               U, nullptr, nullptr, nullptr);
    float* xnext = (l == 0) ? x1 : (float*)d_out;
    k_ln<<<2048, 256, 0, stream>>>(xcur, U, gamma + l * 512, beta + l * 512, xnext,
                                   (l == 0) ? xh : nullptr);
    xcur = xnext;
  }
}

// Round 6
// 198.517 us; speedup vs baseline: 2.8154x; 1.1461x over previous
//
#include <hip/hip_runtime.h>
#include <stdint.h>

typedef _Float16 f16;
typedef _Float16 f16x8 __attribute__((ext_vector_type(8)));
typedef _Float16 f16x4 __attribute__((ext_vector_type(4)));
typedef float f32x4 __attribute__((ext_vector_type(4)));

constexpr int EMB = 512;
constexpr int SEQ = 1024;
constexpr int NH = 8;
constexpr int DHEAD = 64;
constexpr int NTOK = 8192;  // B*S

#define GAS __attribute__((address_space(1)))
#define LAS __attribute__((address_space(3)))

#if __has_builtin(__builtin_amdgcn_exp2f)
#define EXP2F(x) __builtin_amdgcn_exp2f(x)
#else
#define EXP2F(x) exp2f(x)
#endif

static __device__ __forceinline__ void gload_lds16(const void* g, void* l) {
  __builtin_amdgcn_global_load_lds((const GAS void*)g, (LAS void*)l, 16, 0, 0);
}

// ---------------- weight / input packing ----------------

__global__ void k_pack_w(const float* __restrict__ Wq, const float* __restrict__ Wk,
                         const float* __restrict__ Wv, const float* __restrict__ Wo,
                         f16* __restrict__ wqkv, f16* __restrict__ wo) {
  int tid = blockIdx.x * 256 + threadIdx.x;
  if (tid < 2 * 1536 * 128) {  // qkv: [L][1536][512], 4 elems/thread
    int e4 = tid & 127;
    int f = (tid >> 7) % 1536;
    int l = tid / (128 * 1536);
    int part = f >> 9, fr = f & 511;
    const float* src = (part == 0 ? Wq : part == 1 ? Wk : Wv) + (size_t)l * EMB * EMB + (size_t)fr * EMB + e4 * 4;
    float4 v = *(const float4*)src;
    f16x4 hv = {(f16)v.x, (f16)v.y, (f16)v.z, (f16)v.w};
    *(f16x4*)(wqkv + ((size_t)l * 1536 + f) * EMB + e4 * 4) = hv;
  }
  if (tid < 2 * 512 * 128) {  // wo: [L][512][512]
    int e4 = tid & 127;
    int f = (tid >> 7) % 512;
    int l = tid / (128 * 512);
    float4 v = *(const float4*)(Wo + (size_t)l * EMB * EMB + (size_t)f * EMB + e4 * 4);
    f16x4 hv = {(f16)v.x, (f16)v.y, (f16)v.z, (f16)v.w};
    *(f16x4*)(wo + ((size_t)l * 512 + f) * EMB + e4 * 4) = hv;
  }
}

__global__ void k_pack_b(const float* __restrict__ bq, const float* __restrict__ bk,
                         const float* __restrict__ bv, float* __restrict__ bqkv) {
  int tid = blockIdx.x * 256 + threadIdx.x;
  if (tid < 2 * 1536) {
    int f = tid % 1536, l = tid / 1536;
    int part = f >> 9, fr = f & 511;
    bqkv[tid] = (part == 0 ? bq : part == 1 ? bk : bv)[l * EMB + fr];
  }
}

__global__ void k_cvt(const float* __restrict__ x, f16* __restrict__ out) {
  int i = (blockIdx.x * 256 + threadIdx.x) * 8;
  float4 a = *(const float4*)(x + i);
  float4 b = *(const float4*)(x + i + 4);
  f16x8 h = {(f16)a.x, (f16)a.y, (f16)a.z, (f16)a.w, (f16)b.x, (f16)b.y, (f16)b.z, (f16)b.w};
  *(f16x8*)(out + i) = h;
}

// adj -> f16 pre-scaled by 0.125*log2(e), packed in MFMA C-fragment order:
// adjP[((qrow*16 + tile)*16 + lanelow)*4 + n] = adj[qrow][tile*64 + n*16 + lanelow] * c
__global__ void k_pack_adjP(const float* __restrict__ adj, f16* __restrict__ adjP) {
  int tid = blockIdx.x * 256 + threadIdx.x;  // 262144 total
  int lo = tid & 15, t = (tid >> 4) & 15, qrow = tid >> 8;
  const float c = 0.125f * 1.44269504088896f;
  const float* row = adj + (size_t)qrow * SEQ + t * 64 + lo;
  f16x4 v = {(f16)(row[0] * c), (f16)(row[16] * c), (f16)(row[32] * c), (f16)(row[48] * c)};
  *(f16x4*)(adjP + (size_t)tid * 4) = v;
}

// ---------------- GEMM: C[M,N] = A[M,512] * Bw[N,512]^T + bias ----------------
// R5: (a) double-buffered 2-phase schedule (STAGE(t+1) issued before compute(t),
// one barrier per K-step) -- replaces the serial stage->sync->compute of R0;
// (b) XCD-chunked block remap: flat 1D grid, XCD x owns m-tiles [8x,8x+8) for
// ALL n -> A-panel fetched once per XCD L2. LDS 64 KB (2 blocks/CU).
// MODE 0: write f32 U.  MODE 1: scatter Q,K -> [B,H,S,D], V -> Vt [B,H,D,S].

template <int MODE>
__global__ __launch_bounds__(256) void k_gemm(const f16* __restrict__ A, const f16* __restrict__ Bw,
                                              const float* __restrict__ bias, float* __restrict__ Uout,
                                              f16* __restrict__ Qo, f16* __restrict__ Ko,
                                              f16* __restrict__ Vt) {
  __shared__ f16x8 sA[2][1024];  // 32 KB
  __shared__ f16x8 sB[2][1024];  // 32 KB
  const int tid = threadIdx.x;
  const int lane = tid & 63;
  const int lanelow = lane & 15, lanehi = lane >> 4;
  const int wave = tid >> 6;
  const int wm = wave >> 1, wn = wave & 1;
  // XCD-chunked decode: low 6 bits -> m-tile (XCD-major), high bits -> n-tile
  const int flat = blockIdx.x;
  const int mt = (flat & 7) * 8 + ((flat >> 3) & 7);
  const int nt = flat >> 6;
  const int m0 = mt * 128, n0 = nt * 128;

  f32x4 acc[4][4] = {};

  const f16* aB = A + (size_t)m0 * EMB;
  const f16* bB = Bw + (size_t)n0 * EMB;

  int srow[4], scl[4];
#pragma unroll
  for (int p = 0; p < 4; ++p) {
    int i = p * 256 + tid;
    srow[p] = i >> 3;
    scl[p] = (i & 7) ^ (srow[p] & 7);  // pre-swizzled global chunk for linear LDS dest
  }

#define GSTAGE(ktv, bufv)                                                                     \
  {                                                                                           \
    _Pragma("unroll") for (int p = 0; p < 4; ++p) {                                           \
      int i = p * 256 + tid;                                                                  \
      gload_lds16(aB + (size_t)srow[p] * EMB + (ktv) + scl[p] * 8, (char*)sA[bufv] + i * 16); \
      gload_lds16(bB + (size_t)srow[p] * EMB + (ktv) + scl[p] * 8, (char*)sB[bufv] + i * 16); \
    }                                                                                         \
  }

  GSTAGE(0, 0);
  __syncthreads();

  int cur = 0;
  for (int t = 0; t < 8; ++t) {
    if (t < 7) GSTAGE((t + 1) * 64, cur ^ 1);
#pragma unroll
    for (int ks = 0; ks < 2; ++ks) {
      f16x8 af[4], bf[4];
#pragma unroll
      for (int m = 0; m < 4; ++m) {
        int r = wm * 64 + m * 16 + lanelow;
        af[m] = sA[cur][r * 8 + ((ks * 4 + lanehi) ^ (r & 7))];
      }
#pragma unroll
      for (int n = 0; n < 4; ++n) {
        int r = wn * 64 + n * 16 + lanelow;
        bf[n] = sB[cur][r * 8 + ((ks * 4 + lanehi) ^ (r & 7))];
      }
#pragma unroll
      for (int m = 0; m < 4; ++m)
#pragma unroll
        for (int n = 0; n < 4; ++n)
          acc[m][n] = __builtin_amdgcn_mfma_f32_16x16x32_f16(af[m], bf[n], acc[m][n], 0, 0, 0);
    }
    __syncthreads();  // implicit vmcnt(0): next buffer staged; all waves done with cur
    cur ^= 1;
  }
#undef GSTAGE

  // epilogue: C/D layout col = lane&15, row = (lane>>4)*4 + j
#pragma unroll
  for (int n = 0; n < 4; ++n) {
    int col = n0 + wn * 64 + n * 16 + lanelow;
    float bv = bias[col];
#pragma unroll
    for (int m = 0; m < 4; ++m) {
      int rbase = m0 + wm * 64 + m * 16 + lanehi * 4;
#pragma unroll
      for (int j = 0; j < 4; ++j) {
        float v = acc[m][n][j] + bv;
        int row = rbase + j;
        if (MODE == 0) {
          Uout[(size_t)row * EMB + col] = v;
        } else {
          int part = col >> 9, fr = col & 511;
          int hh = fr >> 6, d = fr & 63;
          int b = row >> 10, s = row & 1023;
          int bh = b * NH + hh;
          if (part == 0)
            Qo[((size_t)bh * SEQ + s) * DHEAD + d] = (f16)v;
          else if (part == 1)
            Ko[((size_t)bh * SEQ + s) * DHEAD + d] = (f16)v;
          else
            Vt[((size_t)bh * DHEAD + d) * SEQ + s] = (f16)v;
        }
      }
    }
  }
}

// ---------------- flash attention: LDS-shared K/V tiles, double-buffered ------------
// R4 structure (44us) + R5 XCD-chunked remap: XCD x owns bh in [8x,8x+8) for all
// 8 q-blocks -> per-XCD L2 working set = K+V (2MB) + adjP (2MB) = 4MB = L2 size,
// eliminating the 8x cross-XCD K/V re-fetch of the default round-robin mapping.

__global__ __launch_bounds__(256) void k_attn(const f16* __restrict__ Q, const f16* __restrict__ K,
                                              const f16* __restrict__ Vt, const f16* __restrict__ adjP,
                                              f16* __restrict__ Ob) {
  __shared__ __align__(16) f16 sK[2][4096];   // [buf][64 rows x 8 chunks], swizzled
  __shared__ __align__(16) f16 sV[2][4096];
  __shared__ __align__(16) f16 Pl[4 * 2048];  // per-wave [32][64] P, swizzled
  const int tid = threadIdx.x;
  const int lane = tid & 63;
  const int lanelow = lane & 15, lanehi = lane >> 4;
  const int wave = tid >> 6;
  f16* Plw = Pl + wave * 2048;

  // XCD-chunked decode (bijective on [0,512)): XCD = flat&7 owns 8 bh values, all qblks
  const int flat = blockIdx.x;
  const int bh = (flat & 7) * 8 + ((flat >> 3) & 7);
  const int qblk = flat >> 6;
  const int b = bh >> 3, hh = bh & 7;
  const int q0 = qblk * 128 + wave * 32;

  const f16* Kbase = K + (size_t)bh * SEQ * DHEAD;
  const f16* Vbase = Vt + (size_t)bh * DHEAD * SEQ;

  // staging chunk map: thread handles chunks tid and tid+256 of each tile
  // (512 chunks x 16B = 8KB). Linear LDS dest, inverse-swizzled global source.
  const int c0 = tid, c1 = tid + 256;
  const int r0 = c0 >> 3, ch0 = (c0 & 7) ^ (r0 & 7);
  const int r1 = c1 >> 3, ch1 = (c1 & 7) ^ (r1 & 7);

#define STAGE(tv, bufv)                                                                  \
  {                                                                                      \
    const int kts = (tv)*64;                                                             \
    gload_lds16(Kbase + (size_t)(kts + r0) * DHEAD + ch0 * 8, (char*)sK[bufv] + c0 * 16); \
    gload_lds16(Kbase + (size_t)(kts + r1) * DHEAD + ch1 * 8, (char*)sK[bufv] + c1 * 16); \
    gload_lds16(Vbase + (size_t)r0 * SEQ + kts + ch0 * 8, (char*)sV[bufv] + c0 * 16);     \
    gload_lds16(Vbase + (size_t)r1 * SEQ + kts + ch1 * 8, (char*)sV[bufv] + c1 * 16);     \
  }

  // hoist Q fragments
  f16x8 qf[2][2];
#pragma unroll
  for (int m = 0; m < 2; ++m)
#pragma unroll
    for (int ks = 0; ks < 2; ++ks)
      qf[m][ks] = *(const f16x8*)(Q + ((size_t)bh * SEQ + q0 + m * 16 + lanelow) * DHEAD + ks * 32 + lanehi * 8);

  // adj register prefetch (f16 C-frag packed): 8 x f16x4 = 8 VGPRs
  const f16* Ab = adjP + ((size_t)(q0 + lanehi * 4) * 256 + lanelow) * 4;
  f16x4 ab[2][4];
#define LOAD_A(tv)                                                                    \
  {                                                                                   \
    _Pragma("unroll") for (int m = 0; m < 2; ++m)                                     \
        _Pragma("unroll") for (int j = 0; j < 4; ++j)                                 \
            ab[m][j] = *(const f16x4*)(Ab + ((size_t)(m * 16 + j) * 256 + (tv)*16) * 4); \
  }

  f32x4 oacc[2][4] = {};
  float lpart[2][4] = {};

  STAGE(0, 0);
  LOAD_A(0);
  __syncthreads();

  int cur = 0;
  for (int t = 0; t < 16; ++t) {
    // issue next tile's staging into the other buffer (cover = whole compute phase)
    if (t < 15) STAGE(t + 1, cur ^ 1);

    const f16* sKc = sK[cur];
    const f16* sVc = sV[cur];

    // --- QK^T from LDS K
    f32x4 sacc[2][4] = {};
#pragma unroll
    for (int ks = 0; ks < 2; ++ks) {
      f16x8 kf[4];
#pragma unroll
      for (int n = 0; n < 4; ++n) {
        int r = n * 16 + lanelow;
        kf[n] = *(const f16x8*)(sKc + (r * 8 + ((ks * 4 + lanehi) ^ (r & 7))) * 8);
      }
#pragma unroll
      for (int m = 0; m < 2; ++m)
#pragma unroll
        for (int n = 0; n < 4; ++n)
          sacc[m][n] = __builtin_amdgcn_mfma_f32_16x16x32_f16(qf[m][ks], kf[n], sacc[m][n], 0, 0, 0);
    }

    // snapshot adj(t), prefetch adj(t+1) (cover = exp + PV + next QK)
    f16x4 acur[2][4];
#pragma unroll
    for (int m = 0; m < 2; ++m)
#pragma unroll
      for (int j = 0; j < 4; ++j) acur[m][j] = ab[m][j];
    if (t < 15) LOAD_A(t + 1);

    // --- p = exp2(s * a2); lane-local row sums; stage P in per-wave LDS
#pragma unroll
    for (int m = 0; m < 2; ++m)
#pragma unroll
      for (int j = 0; j < 4; ++j) {
        const int prow = m * 16 + lanehi * 4 + j;
        const f16x4 a4 = acur[m][j];
#pragma unroll
        for (int n = 0; n < 4; ++n) {
          float p = EXP2F(sacc[m][n][j] * (float)a4[n]);
          lpart[m][j] += p;
          Plw[prow * 64 + (((n * 2 + (lanelow >> 3)) ^ (prow & 7)) * 8) + (lanelow & 7)] = (f16)p;
        }
      }

    // --- O += P V from LDS V
#pragma unroll
    for (int ks = 0; ks < 2; ++ks) {
      f16x8 pa[2], vf[4];
#pragma unroll
      for (int m = 0; m < 2; ++m)
        pa[m] = *(const f16x8*)(Plw + (m * 16 + lanelow) * 64 + (((ks * 4 + lanehi) ^ (lanelow & 7)) * 8));
#pragma unroll
      for (int n = 0; n < 4; ++n) {
        int r = n * 16 + lanelow;
        vf[n] = *(const f16x8*)(sVc + (r * 8 + ((ks * 4 + lanehi) ^ (r & 7))) * 8);
      }
#pragma unroll
      for (int m = 0; m < 2; ++m)
#pragma unroll
        for (int n = 0; n < 4; ++n)
          oacc[m][n] = __builtin_amdgcn_mfma_f32_16x16x32_f16(pa[m], vf[n], oacc[m][n], 0, 0, 0);
    }

    __syncthreads();  // implicit vmcnt(0)+lgkmcnt(0): next buffer staged, all waves done with cur
    cur ^= 1;
  }
#undef STAGE
#undef LOAD_A

  // final: one cross-lane reduce of row sums, normalize, write O to [B,S,E] f16
  float linv[2][4];
#pragma unroll
  for (int m = 0; m < 2; ++m)
#pragma unroll
    for (int j = 0; j < 4; ++j) {
      float l = lpart[m][j];
#pragma unroll
      for (int off = 1; off < 16; off <<= 1) l += __shfl_xor(l, off, 16);
      linv[m][j] = 1.0f / l;
    }
#pragma unroll
  for (int m = 0; m < 2; ++m)
#pragma unroll
    for (int n = 0; n < 4; ++n)
#pragma unroll
      for (int j = 0; j < 4; ++j) {
        int qrow = q0 + m * 16 + lanehi * 4 + j;
        float v = oacc[m][n][j] * linv[m][j];
        Ob[((size_t)b * SEQ + qrow) * EMB + hh * DHEAD + n * 16 + lanelow] = (f16)v;
      }
}

// ---------------- residual + layernorm (wave per row) ----------------

__global__ __launch_bounds__(256) void k_ln(const float* __restrict__ xin, const float* __restrict__ Uin,
                                            const float* __restrict__ gamma, const float* __restrict__ beta,
                                            float* __restrict__ xout, f16* __restrict__ xh_out) {
  const int row = blockIdx.x * 4 + (threadIdx.x >> 6);
  const int lane = threadIdx.x & 63;
  const size_t base = (size_t)row * EMB + lane * 8;
  float u[8];
  {
    float4 a0 = *(const float4*)(xin + base);
    float4 a1 = *(const float4*)(xin + base + 4);
    float4 c0 = *(const float4*)(Uin + base);
    float4 c1 = *(const float4*)(Uin + base + 4);
    u[0] = a0.x + c0.x; u[1] = a0.y + c0.y; u[2] = a0.z + c0.z; u[3] = a0.w + c0.w;
    u[4] = a1.x + c1.x; u[5] = a1.y + c1.y; u[6] = a1.z + c1.z; u[7] = a1.w + c1.w;
  }
  float s = 0.f;
#pragma unroll
  for (int i = 0; i < 8; ++i) s += u[i];
#pragma unroll
  for (int off = 1; off < 64; off <<= 1) s += __shfl_xor(s, off, 64);
  const float mu = s * (1.0f / EMB);
  float v = 0.f;
#pragma unroll
  for (int i = 0; i < 8; ++i) { float d = u[i] - mu; v += d * d; }
#pragma unroll
  for (int off = 1; off < 64; off <<= 1) v += __shfl_xor(v, off, 64);
  const float rs = rsqrtf(v * (1.0f / EMB) + 1e-5f);
  const int ci = lane * 8;
  float4 g0 = *(const float4*)(gamma + ci);
  float4 g1 = *(const float4*)(gamma + ci + 4);
  float4 b0 = *(const float4*)(beta + ci);
  float4 b1 = *(const float4*)(beta + ci + 4);
  float g[8] = {g0.x, g0.y, g0.z, g0.w, g1.x, g1.y, g1.z, g1.w};
  float be[8] = {b0.x, b0.y, b0.z, b0.w, b1.x, b1.y, b1.z, b1.w};
  float o[8];
#pragma unroll
  for (int i = 0; i < 8; ++i) o[i] = (u[i] - mu) * rs * g[i] + be[i];
  float4 o0 = {o[0], o[1], o[2], o[3]}, o1 = {o[4], o[5], o[6], o[7]};
  *(float4*)(xout + base) = o0;
  *(float4*)(xout + base + 4) = o1;
  if (xh_out) {
    f16x8 hv = {(f16)o[0], (f16)o[1], (f16)o[2], (f16)o[3], (f16)o[4], (f16)o[5], (f16)o[6], (f16)o[7]};
    *(f16x8*)(xh_out + base) = hv;
  }
}

// ---------------- launch ----------------

extern "C" void kernel_launch(void* const* d_in, const int* in_sizes, int n_in,
                              void* d_out, int out_size, void* d_ws, size_t ws_size,
                              hipStream_t stream) {
  (void)in_sizes; (void)n_in; (void)out_size; (void)ws_size;
  const float* x = (const float*)d_in[0];
  const float* adj = (const float*)d_in[1];
  const float* Wq = (const float*)d_in[2];
  const float* bq = (const float*)d_in[3];
  const float* Wk = (const float*)d_in[4];
  const float* bk = (const float*)d_in[5];
  const float* Wv = (const float*)d_in[6];
  const float* bv = (const float*)d_in[7];
  const float* Wo = (const float*)d_in[8];
  const float* bo = (const float*)d_in[9];
  const float* gamma = (const float*)d_in[10];
  const float* beta = (const float*)d_in[11];

  char* ws = (char*)d_ws;
  size_t off = 0;
  auto alloc = [&](size_t bytes) {
    char* p = ws + off;
    off += (bytes + 255) & ~(size_t)255;
    return p;
  };
  f16* wqkv = (f16*)alloc((size_t)2 * 1536 * 512 * sizeof(f16));
  f16* wo = (f16*)alloc((size_t)2 * 512 * 512 * sizeof(f16));
  float* bqkv = (float*)alloc((size_t)2 * 1536 * sizeof(float));
  f16* adjP = (f16*)alloc((size_t)SEQ * SEQ * sizeof(f16));
  f16* xh = (f16*)alloc((size_t)NTOK * EMB * sizeof(f16));
  f16* Qb = (f16*)alloc((size_t)NTOK * EMB * sizeof(f16));
  f16* Kb = (f16*)alloc((size_t)NTOK * EMB * sizeof(f16));
  f16* Vtb = (f16*)alloc((size_t)NTOK * EMB * sizeof(f16));
  f16* Ob = (f16*)alloc((size_t)NTOK * EMB * sizeof(f16));
  float* U = (float*)alloc((size_t)NTOK * EMB * sizeof(float));
  float* x1 = (float*)alloc((size_t)NTOK * EMB * sizeof(float));

  k_pack_w<<<1536, 256, 0, stream>>>(Wq, Wk, Wv, Wo, wqkv, wo);
  k_pack_b<<<12, 256, 0, stream>>>(bq, bk, bv, bqkv);
  k_pack_adjP<<<1024, 256, 0, stream>>>(adj, adjP);
  k_cvt<<<2048, 256, 0, stream>>>(x, xh);

  const float* xcur = x;
  for (int l = 0; l < 2; ++l) {
    k_gemm<1><<<768, 256, 0, stream>>>(xh, wqkv + (size_t)l * 1536 * 512, bqkv + l * 1536,
                                       nullptr, Qb, Kb, Vtb);
    k_attn<<<512, 256, 0, stream>>>(Qb, Kb, Vtb, adjP, Ob);
    k_gemm<0><<<256, 256, 0, stream>>>(Ob, wo + (size_t)l * 512 * 512, bo + l * 512,
                                       U, nullptr, nullptr, nullptr);
    float* xnext = (l == 0) ? x1 : (float*)d_out;
    k_ln<<<2048, 256, 0, stream>>>(xcur, U, gamma + l * 512, beta + l * 512, xnext,
                                   (l == 0) ? xh : nullptr);
    xcur = xnext;
  }
}

// Round 7
// 177.656 us; speedup vs baseline: 3.1460x; 1.1174x over previous
//
#include <hip/hip_runtime.h>
#include <stdint.h>

typedef _Float16 f16;
typedef _Float16 f16x8 __attribute__((ext_vector_type(8)));
typedef _Float16 f16x4 __attribute__((ext_vector_type(4)));
typedef float f32x4 __attribute__((ext_vector_type(4)));

constexpr int EMB = 512;
constexpr int SEQ = 1024;
constexpr int NH = 8;
constexpr int DHEAD = 64;
constexpr int NTOK = 8192;  // B*S

#define GAS __attribute__((address_space(1)))
#define LAS __attribute__((address_space(3)))

#if __has_builtin(__builtin_amdgcn_exp2f)
#define EXP2F(x) __builtin_amdgcn_exp2f(x)
#else
#define EXP2F(x) exp2f(x)
#endif

static __device__ __forceinline__ void gload_lds16(const void* g, void* l) {
  __builtin_amdgcn_global_load_lds((const GAS void*)g, (LAS void*)l, 16, 0, 0);
}

// ---------------- weight / input packing ----------------

__global__ void k_pack_w(const float* __restrict__ Wq, const float* __restrict__ Wk,
                         const float* __restrict__ Wv, const float* __restrict__ Wo,
                         f16* __restrict__ wqkv, f16* __restrict__ wo) {
  int tid = blockIdx.x * 256 + threadIdx.x;
  if (tid < 2 * 1536 * 128) {  // qkv: [L][1536][512], 4 elems/thread
    int e4 = tid & 127;
    int f = (tid >> 7) % 1536;
    int l = tid / (128 * 1536);
    int part = f >> 9, fr = f & 511;
    const float* src = (part == 0 ? Wq : part == 1 ? Wk : Wv) + (size_t)l * EMB * EMB + (size_t)fr * EMB + e4 * 4;
    float4 v = *(const float4*)src;
    f16x4 hv = {(f16)v.x, (f16)v.y, (f16)v.z, (f16)v.w};
    *(f16x4*)(wqkv + ((size_t)l * 1536 + f) * EMB + e4 * 4) = hv;
  }
  if (tid < 2 * 512 * 128) {  // wo: [L][512][512]
    int e4 = tid & 127;
    int f = (tid >> 7) % 512;
    int l = tid / (128 * 512);
    float4 v = *(const float4*)(Wo + (size_t)l * EMB * EMB + (size_t)f * EMB + e4 * 4);
    f16x4 hv = {(f16)v.x, (f16)v.y, (f16)v.z, (f16)v.w};
    *(f16x4*)(wo + ((size_t)l * 512 + f) * EMB + e4 * 4) = hv;
  }
}

__global__ void k_pack_b(const float* __restrict__ bq, const float* __restrict__ bk,
                         const float* __restrict__ bv, float* __restrict__ bqkv) {
  int tid = blockIdx.x * 256 + threadIdx.x;
  if (tid < 2 * 1536) {
    int f = tid % 1536, l = tid / 1536;
    int part = f >> 9, fr = f & 511;
    bqkv[tid] = (part == 0 ? bq : part == 1 ? bk : bv)[l * EMB + fr];
  }
}

__global__ void k_cvt(const float* __restrict__ x, f16* __restrict__ out) {
  int i = (blockIdx.x * 256 + threadIdx.x) * 8;
  float4 a = *(const float4*)(x + i);
  float4 b = *(const float4*)(x + i + 4);
  f16x8 h = {(f16)a.x, (f16)a.y, (f16)a.z, (f16)a.w, (f16)b.x, (f16)b.y, (f16)b.z, (f16)b.w};
  *(f16x8*)(out + i) = h;
}

// adj -> f16 pre-scaled by 0.125*log2(e), packed in MFMA C-fragment order:
// adjP[((qrow*16 + tile)*16 + lanelow)*4 + n] = adj[qrow][tile*64 + n*16 + lanelow] * c
__global__ void k_pack_adjP(const float* __restrict__ adj, f16* __restrict__ adjP) {
  int tid = blockIdx.x * 256 + threadIdx.x;  // 262144 total
  int lo = tid & 15, t = (tid >> 4) & 15, qrow = tid >> 8;
  const float c = 0.125f * 1.44269504088896f;
  const float* row = adj + (size_t)qrow * SEQ + t * 64 + lo;
  f16x4 v = {(f16)(row[0] * c), (f16)(row[16] * c), (f16)(row[32] * c), (f16)(row[48] * c)};
  *(f16x4*)(adjP + (size_t)tid * 4) = v;
}

// ---------------- GEMM: C[M,N] = A[M,512] * Bw[N,512]^T + bias ----------------
// 2-phase double-buffered staging + XCD-chunked block remap (R5).
// R6: MODE-1 epilogue packs the V^T scatter into f16x4 stores (j -> s contiguous).

template <int MODE>
__global__ __launch_bounds__(256) void k_gemm(const f16* __restrict__ A, const f16* __restrict__ Bw,
                                              const float* __restrict__ bias, float* __restrict__ Uout,
                                              f16* __restrict__ Qo, f16* __restrict__ Ko,
                                              f16* __restrict__ Vt) {
  __shared__ f16x8 sA[2][1024];  // 32 KB
  __shared__ f16x8 sB[2][1024];  // 32 KB
  const int tid = threadIdx.x;
  const int lane = tid & 63;
  const int lanelow = lane & 15, lanehi = lane >> 4;
  const int wave = tid >> 6;
  const int wm = wave >> 1, wn = wave & 1;
  // XCD-chunked decode: low 6 bits -> m-tile (XCD-major), high bits -> n-tile
  const int flat = blockIdx.x;
  const int mt = (flat & 7) * 8 + ((flat >> 3) & 7);
  const int nt = flat >> 6;
  const int m0 = mt * 128, n0 = nt * 128;

  f32x4 acc[4][4] = {};

  const f16* aB = A + (size_t)m0 * EMB;
  const f16* bB = Bw + (size_t)n0 * EMB;

  int srow[4], scl[4];
#pragma unroll
  for (int p = 0; p < 4; ++p) {
    int i = p * 256 + tid;
    srow[p] = i >> 3;
    scl[p] = (i & 7) ^ (srow[p] & 7);  // pre-swizzled global chunk for linear LDS dest
  }

#define GSTAGE(ktv, bufv)                                                                     \
  {                                                                                           \
    _Pragma("unroll") for (int p = 0; p < 4; ++p) {                                           \
      int i = p * 256 + tid;                                                                  \
      gload_lds16(aB + (size_t)srow[p] * EMB + (ktv) + scl[p] * 8, (char*)sA[bufv] + i * 16); \
      gload_lds16(bB + (size_t)srow[p] * EMB + (ktv) + scl[p] * 8, (char*)sB[bufv] + i * 16); \
    }                                                                                         \
  }

  GSTAGE(0, 0);
  __syncthreads();

  int cur = 0;
  for (int t = 0; t < 8; ++t) {
    if (t < 7) GSTAGE((t + 1) * 64, cur ^ 1);
#pragma unroll
    for (int ks = 0; ks < 2; ++ks) {
      f16x8 af[4], bf[4];
#pragma unroll
      for (int m = 0; m < 4; ++m) {
        int r = wm * 64 + m * 16 + lanelow;
        af[m] = sA[cur][r * 8 + ((ks * 4 + lanehi) ^ (r & 7))];
      }
#pragma unroll
      for (int n = 0; n < 4; ++n) {
        int r = wn * 64 + n * 16 + lanelow;
        bf[n] = sB[cur][r * 8 + ((ks * 4 + lanehi) ^ (r & 7))];
      }
      __builtin_amdgcn_s_setprio(1);
#pragma unroll
      for (int m = 0; m < 4; ++m)
#pragma unroll
        for (int n = 0; n < 4; ++n)
          acc[m][n] = __builtin_amdgcn_mfma_f32_16x16x32_f16(af[m], bf[n], acc[m][n], 0, 0, 0);
      __builtin_amdgcn_s_setprio(0);
    }
    __syncthreads();  // implicit vmcnt(0): next buffer staged; all waves done with cur
    cur ^= 1;
  }
#undef GSTAGE

  // epilogue: C/D layout col = lane&15, row = (lane>>4)*4 + j
#pragma unroll
  for (int n = 0; n < 4; ++n) {
    int col = n0 + wn * 64 + n * 16 + lanelow;
    float bv = bias[col];
    if (MODE == 1 && (col >> 9) == 2) {
      // V-part: j -> s contiguous in Vt[bh][d][s]; pack 4 per store
      int fr = col & 511, hh = fr >> 6, d = fr & 63;
#pragma unroll
      for (int m = 0; m < 4; ++m) {
        int rbase = m0 + wm * 64 + m * 16 + lanehi * 4;
        int b = rbase >> 10, s = rbase & 1023;
        f16x4 pv = {(f16)(acc[m][n][0] + bv), (f16)(acc[m][n][1] + bv),
                    (f16)(acc[m][n][2] + bv), (f16)(acc[m][n][3] + bv)};
        *(f16x4*)(Vt + ((size_t)(b * NH + hh) * DHEAD + d) * SEQ + s) = pv;
      }
    } else {
#pragma unroll
      for (int m = 0; m < 4; ++m) {
        int rbase = m0 + wm * 64 + m * 16 + lanehi * 4;
#pragma unroll
        for (int j = 0; j < 4; ++j) {
          float v = acc[m][n][j] + bv;
          int row = rbase + j;
          if (MODE == 0) {
            Uout[(size_t)row * EMB + col] = v;
          } else {
            int part = col >> 9, fr = col & 511;
            int hh = fr >> 6, d = fr & 63;
            int b = row >> 10, s = row & 1023;
            int bh = b * NH + hh;
            if (part == 0)
              Qo[((size_t)bh * SEQ + s) * DHEAD + d] = (f16)v;
            else
              Ko[((size_t)bh * SEQ + s) * DHEAD + d] = (f16)v;
          }
        }
      }
    }
  }
}

// ---------------- flash attention ----------------
// R6: KVBLK=128 (8 barriers instead of 16), computed as two 64-halves reusing
// the per-wave P buffer; exp->PV split by k-half (PV ks=0 only needs P n=0,1)
// to overlap exp VALU with PV MFMA; setprio around MFMA clusters.
// LDS: K dbuf 32K + V dbuf 32K + P 16K = 80KB -> 2 blocks/CU.

__global__ __launch_bounds__(256) void k_attn(const f16* __restrict__ Q, const f16* __restrict__ K,
                                              const f16* __restrict__ Vt, const f16* __restrict__ adjP,
                                              f16* __restrict__ Ob) {
  __shared__ __align__(16) f16 sK[2][8192];   // [buf][128 rows x 8 chunks], swizzled
  __shared__ __align__(16) f16 sV[2][8192];   // [buf][64 rows x 16 chunks], swizzled
  __shared__ __align__(16) f16 Pl[4 * 2048];  // per-wave [32][64] P, swizzled
  const int tid = threadIdx.x;
  const int lane = tid & 63;
  const int lanelow = lane & 15, lanehi = lane >> 4;
  const int wave = tid >> 6;
  f16* Plw = Pl + wave * 2048;

  // XCD-chunked decode (bijective on [0,512)): XCD = flat&7 owns 8 bh values, all qblks
  const int flat = blockIdx.x;
  const int bh = (flat & 7) * 8 + ((flat >> 3) & 7);
  const int qblk = flat >> 6;
  const int b = bh >> 3, hh = bh & 7;
  const int q0 = qblk * 128 + wave * 32;

  const f16* Kbase = K + (size_t)bh * SEQ * DHEAD;
  const f16* Vbase = Vt + (size_t)bh * DHEAD * SEQ;

  // staging maps (linear LDS dest, inverse-swizzled global source).
  // K-tile: 128 rows x 8 chunks = 1024 chunks; V-tile: 64 rows x 16 chunks = 1024.
  int kr[4], kc[4], vr[4], vc[4];
#pragma unroll
  for (int p = 0; p < 4; ++p) {
    int c = p * 256 + tid;
    kr[p] = c >> 3;
    kc[p] = (c & 7) ^ (kr[p] & 7);
    vr[p] = c >> 4;
    vc[p] = (c & 15) ^ (vr[p] & 7);
  }

#define STAGE(tv, bufv)                                                                       \
  {                                                                                           \
    const int kts = (tv)*128;                                                                 \
    _Pragma("unroll") for (int p = 0; p < 4; ++p) {                                           \
      int c = p * 256 + tid;                                                                  \
      gload_lds16(Kbase + (size_t)(kts + kr[p]) * DHEAD + kc[p] * 8, (char*)sK[bufv] + c * 16); \
      gload_lds16(Vbase + (size_t)vr[p] * SEQ + kts + vc[p] * 8, (char*)sV[bufv] + c * 16);     \
    }                                                                                         \
  }

  // hoist Q fragments
  f16x8 qf[2][2];
#pragma unroll
  for (int m = 0; m < 2; ++m)
#pragma unroll
    for (int ks = 0; ks < 2; ++ks)
      qf[m][ks] = *(const f16x8*)(Q + ((size_t)bh * SEQ + q0 + m * 16 + lanelow) * DHEAD + ks * 32 + lanehi * 8);

  // adj register prefetch (f16 C-frag packed)
  const f16* Ab = adjP + ((size_t)(q0 + lanehi * 4) * 256 + lanelow) * 4;
  f16x4 ab[2][4];
#define LOAD_A(tv)                                                                    \
  {                                                                                   \
    _Pragma("unroll") for (int m = 0; m < 2; ++m)                                     \
        _Pragma("unroll") for (int j = 0; j < 4; ++j)                                 \
            ab[m][j] = *(const f16x4*)(Ab + ((size_t)(m * 16 + j) * 256 + (tv)*16) * 4); \
  }

  f32x4 oacc[2][4] = {};
  float lpart[2][4] = {};

  STAGE(0, 0);
  LOAD_A(0);
  __syncthreads();

  int cur = 0;
  for (int t = 0; t < 8; ++t) {
    if (t < 7) STAGE(t + 1, cur ^ 1);

    const f16* sKc = sK[cur];
    const f16* sVc = sV[cur];

#pragma unroll
    for (int hs = 0; hs < 2; ++hs) {
      const int t2 = t * 2 + hs;  // 64-wide sub-tile index (0..15)

      // --- QK^T from LDS K (rows hs*64 .. hs*64+63)
      f32x4 sacc[2][4] = {};
#pragma unroll
      for (int ks = 0; ks < 2; ++ks) {
        f16x8 kf[4];
#pragma unroll
        for (int n = 0; n < 4; ++n) {
          int r = hs * 64 + n * 16 + lanelow;
          kf[n] = *(const f16x8*)(sKc + (r * 8 + ((ks * 4 + lanehi) ^ (r & 7))) * 8);
        }
        __builtin_amdgcn_s_setprio(1);
#pragma unroll
        for (int m = 0; m < 2; ++m)
#pragma unroll
          for (int n = 0; n < 4; ++n)
            sacc[m][n] = __builtin_amdgcn_mfma_f32_16x16x32_f16(qf[m][ks], kf[n], sacc[m][n], 0, 0, 0);
        __builtin_amdgcn_s_setprio(0);
      }

      // snapshot adj(t2), prefetch adj(t2+1)
      f16x4 acur[2][4];
#pragma unroll
      for (int m = 0; m < 2; ++m)
#pragma unroll
        for (int j = 0; j < 4; ++j) acur[m][j] = ab[m][j];
      if (t2 < 15) LOAD_A(t2 + 1);

      // --- exp + PV interleaved by k-half: PV(ks=nh) only needs P cols of n=2nh,2nh+1
#pragma unroll
      for (int nh = 0; nh < 2; ++nh) {
#pragma unroll
        for (int m = 0; m < 2; ++m)
#pragma unroll
          for (int j = 0; j < 4; ++j) {
            const int prow = m * 16 + lanehi * 4 + j;
            const f16x4 a4 = acur[m][j];
#pragma unroll
            for (int nn = 0; nn < 2; ++nn) {
              const int n = nh * 2 + nn;
              float p = EXP2F(sacc[m][n][j] * (float)a4[n]);
              lpart[m][j] += p;
              Plw[prow * 64 + (((n * 2 + (lanelow >> 3)) ^ (prow & 7)) * 8) + (lanelow & 7)] = (f16)p;
            }
          }
        f16x8 pa[2], vf[4];
#pragma unroll
        for (int m = 0; m < 2; ++m)
          pa[m] = *(const f16x8*)(Plw + (m * 16 + lanelow) * 64 + (((nh * 4 + lanehi) ^ (lanelow & 7)) * 8));
#pragma unroll
        for (int n = 0; n < 4; ++n) {
          int r = n * 16 + lanelow;
          vf[n] = *(const f16x8*)(sVc + (r * 16 + ((hs * 8 + nh * 4 + lanehi) ^ (r & 7))) * 8);
        }
        __builtin_amdgcn_s_setprio(1);
#pragma unroll
        for (int m = 0; m < 2; ++m)
#pragma unroll
          for (int n = 0; n < 4; ++n)
            oacc[m][n] = __builtin_amdgcn_mfma_f32_16x16x32_f16(pa[m], vf[n], oacc[m][n], 0, 0, 0);
        __builtin_amdgcn_s_setprio(0);
      }
    }

    __syncthreads();  // next buffer staged; all waves done with cur
    cur ^= 1;
  }
#undef STAGE
#undef LOAD_A

  // final: one cross-lane reduce of row sums, normalize, write O to [B,S,E] f16
  float linv[2][4];
#pragma unroll
  for (int m = 0; m < 2; ++m)
#pragma unroll
    for (int j = 0; j < 4; ++j) {
      float l = lpart[m][j];
#pragma unroll
      for (int off = 1; off < 16; off <<= 1) l += __shfl_xor(l, off, 16);
      linv[m][j] = 1.0f / l;
    }
#pragma unroll
  for (int m = 0; m < 2; ++m)
#pragma unroll
    for (int n = 0; n < 4; ++n)
#pragma unroll
      for (int j = 0; j < 4; ++j) {
        int qrow = q0 + m * 16 + lanehi * 4 + j;
        float v = oacc[m][n][j] * linv[m][j];
        Ob[((size_t)b * SEQ + qrow) * EMB + hh * DHEAD + n * 16 + lanelow] = (f16)v;
      }
}

// ---------------- residual + layernorm (wave per row) ----------------

__global__ __launch_bounds__(256) void k_ln(const float* __restrict__ xin, const float* __restrict__ Uin,
                                            const float* __restrict__ gamma, const float* __restrict__ beta,
                                            float* __restrict__ xout, f16* __restrict__ xh_out) {
  const int row = blockIdx.x * 4 + (threadIdx.x >> 6);
  const int lane = threadIdx.x & 63;
  const size_t base = (size_t)row * EMB + lane * 8;
  float u[8];
  {
    float4 a0 = *(const float4*)(xin + base);
    float4 a1 = *(const float4*)(xin + base + 4);
    float4 c0 = *(const float4*)(Uin + base);
    float4 c1 = *(const float4*)(Uin + base + 4);
    u[0] = a0.x + c0.x; u[1] = a0.y + c0.y; u[2] = a0.z + c0.z; u[3] = a0.w + c0.w;
    u[4] = a1.x + c1.x; u[5] = a1.y + c1.y; u[6] = a1.z + c1.z; u[7] = a1.w + c1.w;
  }
  float s = 0.f;
#pragma unroll
  for (int i = 0; i < 8; ++i) s += u[i];
#pragma unroll
  for (int off = 1; off < 64; off <<= 1) s += __shfl_xor(s, off, 64);
  const float mu = s * (1.0f / EMB);
  float v = 0.f;
#pragma unroll
  for (int i = 0; i < 8; ++i) { float d = u[i] - mu; v += d * d; }
#pragma unroll
  for (int off = 1; off < 64; off <<= 1) v += __shfl_xor(v, off, 64);
  const float rs = rsqrtf(v * (1.0f / EMB) + 1e-5f);
  const int ci = lane * 8;
  float4 g0 = *(const float4*)(gamma + ci);
  float4 g1 = *(const float4*)(gamma + ci + 4);
  float4 b0 = *(const float4*)(beta + ci);
  float4 b1 = *(const float4*)(beta + ci + 4);
  float g[8] = {g0.x, g0.y, g0.z, g0.w, g1.x, g1.y, g1.z, g1.w};
  float be[8] = {b0.x, b0.y, b0.z, b0.w, b1.x, b1.y, b1.z, b1.w};
  float o[8];
#pragma unroll
  for (int i = 0; i < 8; ++i) o[i] = (u[i] - mu) * rs * g[i] + be[i];
  float4 o0 = {o[0], o[1], o[2], o[3]}, o1 = {o[4], o[5], o[6], o[7]};
  *(float4*)(xout + base) = o0;
  *(float4*)(xout + base + 4) = o1;
  if (xh_out) {
    f16x8 hv = {(f16)o[0], (f16)o[1], (f16)o[2], (f16)o[3], (f16)o[4], (f16)o[5], (f16)o[6], (f16)o[7]};
    *(f16x8*)(xh_out + base) = hv;
  }
}

// ---------------- launch ----------------

extern "C" void kernel_launch(void* const* d_in, const int* in_sizes, int n_in,
                              void* d_out, int out_size, void* d_ws, size_t ws_size,
                              hipStream_t stream) {
  (void)in_sizes; (void)n_in; (void)out_size; (void)ws_size;
  const float* x = (const float*)d_in[0];
  const float* adj = (const float*)d_in[1];
  const float* Wq = (const float*)d_in[2];
  const float* bq = (const float*)d_in[3];
  const float* Wk = (const float*)d_in[4];
  const float* bk = (const float*)d_in[5];
  const float* Wv = (const float*)d_in[6];
  const float* bv = (const float*)d_in[7];
  const float* Wo = (const float*)d_in[8];
  const float* bo = (const float*)d_in[9];
  const float* gamma = (const float*)d_in[10];
  const float* beta = (const float*)d_in[11];

  char* ws = (char*)d_ws;
  size_t off = 0;
  auto alloc = [&](size_t bytes) {
    char* p = ws + off;
    off += (bytes + 255) & ~(size_t)255;
    return p;
  };
  f16* wqkv = (f16*)alloc((size_t)2 * 1536 * 512 * sizeof(f16));
  f16* wo = (f16*)alloc((size_t)2 * 512 * 512 * sizeof(f16));
  float* bqkv = (float*)alloc((size_t)2 * 1536 * sizeof(float));
  f16* adjP = (f16*)alloc((size_t)SEQ * SEQ * sizeof(f16));
  f16* xh = (f16*)alloc((size_t)NTOK * EMB * sizeof(f16));
  f16* Qb = (f16*)alloc((size_t)NTOK * EMB * sizeof(f16));
  f16* Kb = (f16*)alloc((size_t)NTOK * EMB * sizeof(f16));
  f16* Vtb = (f16*)alloc((size_t)NTOK * EMB * sizeof(f16));
  f16* Ob = (f16*)alloc((size_t)NTOK * EMB * sizeof(f16));
  float* U = (float*)alloc((size_t)NTOK * EMB * sizeof(float));
  float* x1 = (float*)alloc((size_t)NTOK * EMB * sizeof(float));

  k_pack_w<<<1536, 256, 0, stream>>>(Wq, Wk, Wv, Wo, wqkv, wo);
  k_pack_b<<<12, 256, 0, stream>>>(bq, bk, bv, bqkv);
  k_pack_adjP<<<1024, 256, 0, stream>>>(adj, adjP);
  k_cvt<<<2048, 256, 0, stream>>>(x, xh);

  const float* xcur = x;
  for (int l = 0; l < 2; ++l) {
    k_gemm<1><<<768, 256, 0, stream>>>(xh, wqkv + (size_t)l * 1536 * 512, bqkv + l * 1536,
                                       nullptr, Qb, Kb, Vtb);
    k_attn<<<512, 256, 0, stream>>>(Qb, Kb, Vtb, adjP, Ob);
    k_gemm<0><<<256, 256, 0, stream>>>(Ob, wo + (size_t)l * 512 * 512, bo + l * 512,
                                       U, nullptr, nullptr, nullptr);
    float* xnext = (l == 0) ? x1 : (float*)d_out;
    k_ln<<<2048, 256, 0, stream>>>(xcur, U, gamma + l * 512, beta + l * 512, xnext,
                                   (l == 0) ? xh : nullptr);
    xcur = xnext;
  }
}